// Round 3
// baseline (482.753 us; speedup 1.0000x reference)
//
#include <hip/hip_runtime.h>
#include <math.h>

typedef __attribute__((ext_vector_type(8))) __bf16 bf16x8;
typedef __attribute__((ext_vector_type(4))) float f32x4;

__device__ inline unsigned short f2bf(float f) {  // RNE
    unsigned int i = __float_as_uint(f);
    unsigned int r = i + 0x7fffu + ((i >> 16) & 1u);
    return (unsigned short)(r >> 16);
}
__device__ inline float bf2f(unsigned short u) {
    return __uint_as_float(((unsigned int)u) << 16);
}

// ---------------- prelude: MLP(+s1/d1) + weight-cast + graph starts + degree hist + pv2 ----
// Block ranges: [0,mlpB) mlp | [+f2bfB) weight cast | [+gsB) graph starts | [+histB) hist |
// last block: pv2 = W2^T {a_s2, a_d2}.
// MLP weights are read DIRECTLY from global with uniform compile-time indices -> scalar
// loads (s_load) through the constant cache; no LDS staging (the old ds_read-per-FMA path
// was DS-issue bound: ~2576 ds_read_b32 per wave).
__global__ __launch_bounds__(256) void prelude_kernel(
    const float* __restrict__ x,
    const float* __restrict__ w1, const float* __restrict__ b1,
    const float* __restrict__ w2, const float* __restrict__ b2,
    const float* __restrict__ w3, const float* __restrict__ b3,
    unsigned short* __restrict__ h0, int n,
    const float* __restrict__ g0, const float* __restrict__ g1, const float* __restrict__ g2,
    const float* __restrict__ g3, const float* __restrict__ g4,
    unsigned short* __restrict__ wbAll,
    const int* __restrict__ batch, int* __restrict__ gstart, int G,
    const int* __restrict__ dst, int* __restrict__ deg, int E,
    int mlpB, int f2bfB, int gsB, int histB,
    const float* __restrict__ as1, const float* __restrict__ ad1,
    float* __restrict__ s1out, float* __restrict__ d1out,
    const float* __restrict__ as2, const float* __restrict__ ad2,
    float* __restrict__ pv2) {
    int b = blockIdx.x;
    int tid = threadIdx.x;
    if (b < mlpB) {
        __shared__ float4 psd1q[32];  // interleaved {s,d} pairs: psd1[o] at ((float2*)psd1q)[o]
        if (tid >= 192) {  // p-vec for layer 1: p = W1^T a  (g0 is g1w, [128][64])
            int i = tid - 192;
            float s = 0.f, d = 0.f;
            for (int o = 0; o < 128; o++) {
                float w = g0[o * 64 + i];
                s += as1[o] * w;
                d += ad1[o] * w;
            }
            ((float2*)psd1q)[i] = make_float2(s, d);
        }
        __syncthreads();
        int node = b * 256 + tid;
        if (node >= n) return;
        float xv = x[node];
        float t1[16], t2[32];
#pragma unroll
        for (int i = 0; i < 16; i++) t1[i] = fmaxf(w1[i] * xv + b1[i], 0.f);
        const float4* w2v = (const float4*)w2;  // [32][16] -> 4 float4 per row
#pragma unroll
        for (int o = 0; o < 32; o++) {
            float a = b2[o];
#pragma unroll
            for (int q = 0; q < 4; q++) {
                float4 wv = w2v[o * 4 + q];
                a += wv.x * t1[q * 4] + wv.y * t1[q * 4 + 1] + wv.z * t1[q * 4 + 2] +
                     wv.w * t1[q * 4 + 3];
            }
            t2[o] = fmaxf(a, 0.f);
        }
        const float4* w3v = (const float4*)w3;  // [64][32] -> 8 float4 per row
        float sdot = 0.f, ddot = 0.f;
        uint4* gp = (uint4*)(h0 + (size_t)node * 64);
#pragma unroll
        for (int c = 0; c < 8; c++) {
            unsigned int wvec[4];
#pragma unroll
            for (int p = 0; p < 4; p++) {
                int o = c * 8 + p * 2;
                float a0 = b3[o], a1 = b3[o + 1];
#pragma unroll
                for (int q = 0; q < 8; q++) {
                    float4 wa = w3v[o * 8 + q];
                    float4 wb = w3v[o * 8 + 8 + q];
                    a0 += wa.x * t2[q * 4] + wa.y * t2[q * 4 + 1] + wa.z * t2[q * 4 + 2] +
                          wa.w * t2[q * 4 + 3];
                    a1 += wb.x * t2[q * 4] + wb.y * t2[q * 4 + 1] + wb.z * t2[q * 4 + 2] +
                          wb.w * t2[q * 4 + 3];
                }
                float r0 = fmaxf(a0, 0.f), r1 = fmaxf(a1, 0.f);
                float4 qsd = psd1q[o >> 1];  // {s_o, d_o, s_{o+1}, d_{o+1}}
                sdot += r0 * qsd.x + r1 * qsd.z;
                ddot += r0 * qsd.y + r1 * qsd.w;
                wvec[p] = (unsigned)f2bf(r0) | ((unsigned)f2bf(r1) << 16);
            }
            gp[c] = make_uint4(wvec[0], wvec[1], wvec[2], wvec[3]);
        }
        s1out[node] = sdot;
        d1out[node] = ddot;
    } else if (b < mlpB + f2bfB) {
        int i = (b - mlpB) * 256 + tid;
        // segment offsets: 0, 8192, 40960, 73728, 81920, end 83968
        float v;
        if (i < 8192) v = g0[i];
        else if (i < 40960) v = g1[i - 8192];
        else if (i < 73728) v = g2[i - 40960];
        else if (i < 81920) v = g3[i - 73728];
        else if (i < 83968) v = g4[i - 81920];
        else return;
        wbAll[i] = f2bf(v);
    } else if (b < mlpB + f2bfB + gsB) {
        int g = (b - mlpB - f2bfB) * 256 + tid;
        if (g > G) return;
        if (g == G) { gstart[G] = n; return; }
        int lo = 0, hi = n;
        while (lo < hi) {
            int mid = (lo + hi) >> 1;
            if (batch[mid] < g) lo = mid + 1;
            else hi = mid;
        }
        gstart[g] = lo;
    } else if (b < mlpB + f2bfB + gsB + histB) {
        int e = (b - mlpB - f2bfB - gsB) * 256 + tid;
        if (e >= E + n) return;
        int d = (e < E) ? dst[e] : (e - E);
        atomicAdd(&deg[d], 1);
    } else {
        // pv2 = W2^T {a_s2 | a_d2}; g1 is g2w [256][128]
        if (tid < 128) {
            float s = 0.f;
            for (int o = 0; o < 256; o++) s += as2[o] * g1[o * 128 + tid];
            pv2[tid] = s;
        } else {
            int c = tid - 128;
            float s = 0.f;
            for (int o = 0; o < 256; o++) s += ad2[o] * g1[o * 128 + c];
            pv2[128 + c] = s;
        }
    }
}

// ---------------- bf16 MFMA GEMM, 128xBN tile, BK=64 ----------------
// EPI: 0 = raw store + raw-acc dot with avs/avd (scheme-T layers)
//      1 = bias+relu store + post-relu dot with avs/avd (feeds a scheme-A layer)
//      2 = bias+relu store only
template <int BN, int EPI>
__global__ __launch_bounds__(256) void gemm_mfma(
    const unsigned short* __restrict__ A, const unsigned short* __restrict__ Wb,
    unsigned short* __restrict__ Cb,
    const float* __restrict__ avs, const float* __restrict__ avd,
    float* __restrict__ as_, float* __restrict__ ad_,
    const float* __restrict__ bias, int n, int K, int O) {
    constexpr int SN = BN / 32;
    __shared__ unsigned short As[128][72];  // +8 pad: frag reads <=2-way banks (free)
    __shared__ unsigned short Ws[BN][72];
    int tid = threadIdx.x;
    int row0 = blockIdx.x * 128, col0 = blockIdx.y * BN;
    int w = tid >> 6, lane = tid & 63;
    int wr = w >> 1, wc = w & 1;
    int quad = lane >> 4, l15 = lane & 15;
    f32x4 acc[4][SN];
#pragma unroll
    for (int mi = 0; mi < 4; mi++)
#pragma unroll
        for (int ni = 0; ni < SN; ni++) acc[mi][ni] = (f32x4){0.f, 0.f, 0.f, 0.f};

    for (int k0 = 0; k0 < K; k0 += 64) {
#pragma unroll
        for (int i = tid; i < 1024; i += 256) {
            int r = i >> 3, c8 = i & 7;
            int gr = row0 + r;
            uint4 v = make_uint4(0u, 0u, 0u, 0u);
            if (gr < n) v = *(const uint4*)(A + (size_t)gr * K + k0 + c8 * 8);
            *(uint4*)&As[r][c8 * 8] = v;
        }
#pragma unroll
        for (int i = tid; i < BN * 8; i += 256) {
            int r = i >> 3, c8 = i & 7;
            uint4 v = *(const uint4*)(Wb + (size_t)(col0 + r) * K + k0 + c8 * 8);
            *(uint4*)&Ws[r][c8 * 8] = v;
        }
        __syncthreads();
#pragma unroll
        for (int kk = 0; kk < 64; kk += 32) {
            bf16x8 bfr[SN];
#pragma unroll
            for (int ni = 0; ni < SN; ni++)
                bfr[ni] = *(const bf16x8*)&Ws[wc * (BN / 2) + ni * 16 + l15][kk + quad * 8];
#pragma unroll
            for (int mi = 0; mi < 4; mi++) {
                bf16x8 afr = *(const bf16x8*)&As[wr * 64 + mi * 16 + l15][kk + quad * 8];
#pragma unroll
                for (int ni = 0; ni < SN; ni++)
                    acc[mi][ni] = __builtin_amdgcn_mfma_f32_16x16x32_bf16(afr, bfr[ni],
                                                                          acc[mi][ni], 0, 0, 0);
            }
        }
        __syncthreads();
    }
    float avsv[SN], avdv[SN], bv[SN];
    int gc[SN];
#pragma unroll
    for (int ni = 0; ni < SN; ni++) {
        gc[ni] = col0 + wc * (BN / 2) + ni * 16 + l15;
        if constexpr (EPI != 2) {
            avsv[ni] = avs[gc[ni]];
            avdv[ni] = avd[gc[ni]];
        }
        if constexpr (EPI >= 1) bv[ni] = bias[gc[ni]];
    }
#pragma unroll
    for (int mi = 0; mi < 4; mi++) {
        int gm0 = row0 + wr * 64 + mi * 16 + quad * 4;
        float ps[4] = {0.f, 0.f, 0.f, 0.f}, pd[4] = {0.f, 0.f, 0.f, 0.f};
#pragma unroll
        for (int ni = 0; ni < SN; ni++) {
#pragma unroll
            for (int r = 0; r < 4; r++) {
                float d = acc[mi][ni][r];
                if constexpr (EPI >= 1) d = fmaxf(d + bv[ni], 0.f);
                int gm = gm0 + r;
                if (gm < n) Cb[(size_t)gm * O + gc[ni]] = f2bf(d);
                if constexpr (EPI != 2) {
                    ps[r] += d * avsv[ni];
                    pd[r] += d * avdv[ni];
                }
            }
        }
        if constexpr (EPI != 2) {
#pragma unroll
            for (int r = 0; r < 4; r++) {
#pragma unroll
                for (int m = 1; m <= 8; m <<= 1) {
                    ps[r] += __shfl_xor(ps[r], m);
                    pd[r] += __shfl_xor(pd[r], m);
                }
            }
            if (l15 == 0) {
#pragma unroll
                for (int r = 0; r < 4; r++) {
                    int gm = gm0 + r;
                    if (gm < n) {
                        atomicAdd(&as_[gm], ps[r]);
                        atomicAdd(&ad_[gm], pd[r]);
                    }
                }
            }
        }
    }
}

// ---------------- scan: per-1024-chunk sums ----------------
__global__ void scan_block_sums(const int* __restrict__ deg, int* __restrict__ bsums, int n) {
    __shared__ int sdata[256];
    int tid = threadIdx.x;
    int base = blockIdx.x * 1024 + tid * 4;
    int s = 0;
    for (int i = 0; i < 4; i++) {
        int g = base + i;
        if (g < n) s += deg[g];
    }
    sdata[tid] = s;
    __syncthreads();
    for (int off = 128; off > 0; off >>= 1) {
        if (tid < off) sdata[tid] += sdata[tid + off];
        __syncthreads();
    }
    if (tid == 0) bsums[blockIdx.x] = sdata[0];
}

// ---------------- scan_write: inline bsums prefix (nb <= 256) + rowptr/cursor ----------------
__global__ void scan_write(const int* __restrict__ deg, const int* __restrict__ bsums,
                           int* __restrict__ rowptr, int* __restrict__ cursor, int n, int nb) {
    __shared__ int sdata[256];
    int tid = threadIdx.x;
    sdata[tid] = (tid < blockIdx.x && tid < nb) ? bsums[tid] : 0;
    __syncthreads();
    for (int off = 128; off > 0; off >>= 1) {
        if (tid < off) sdata[tid] += sdata[tid + off];
        __syncthreads();
    }
    int base = sdata[0];
    __syncthreads();
    int gbase = blockIdx.x * 1024 + tid * 4;
    int v[4];
    int s = 0;
    for (int i = 0; i < 4; i++) {
        int g = gbase + i;
        v[i] = (g < n) ? deg[g] : 0;
        s += v[i];
    }
    sdata[tid] = s;
    __syncthreads();
    for (int off = 1; off < 256; off <<= 1) {  // inclusive Hillis-Steele
        int t = (tid >= off) ? sdata[tid - off] : 0;
        __syncthreads();
        sdata[tid] += t;
        __syncthreads();
    }
    int excl = sdata[tid] - s + base;
    for (int i = 0; i < 4; i++) {
        int g = gbase + i;
        if (g < n) { rowptr[g] = excl; cursor[g] = excl; }
        excl += v[i];
    }
    if (blockIdx.x == gridDim.x - 1 && tid == 255) rowptr[n] = base + sdata[255];
}

__global__ void scatter_kernel(const int* __restrict__ esrc_in, const int* __restrict__ edst_in,
                               int* __restrict__ cursor, int* __restrict__ esrc, int E, int n) {
    int e = blockIdx.x * 256 + threadIdx.x;
    if (e >= E + n) return;
    int s, d;
    if (e < E) { s = esrc_in[e]; d = edst_in[e]; }
    else { s = e - E; d = e - E; }
    int pos = atomicAdd(&cursor[d], 1);
    esrc[pos] = s;
}

// ---------------- GAT aggregation: 16-lane group per dst node (4 nodes/wave) ----------------
// BIASRELU=false: scheme-A (aggregate-first) — raw weighted sum, bias/relu applied by the
// following GEMM. BIASRELU=true: scheme-T — add bias, relu.
// Fast path deg<=16: one edge per group lane; all shuffles (xor masks <16, computed src
// lanes (lane&48)|cidx) stay inside the 16-lane group.
// Also zeroes zeroBuf (a later layer's alpha accumulators) as a grid-stride chore.
template <int O, bool BIASRELU>
__global__ __launch_bounds__(256) void gat_aggregate(
    const unsigned short* __restrict__ hl, const float* __restrict__ as_,
    const float* __restrict__ ad_, const int* __restrict__ rowptr,
    const int* __restrict__ esrc, const float* __restrict__ bias,
    unsigned short* __restrict__ hout, int n, float* __restrict__ zeroBuf, int zeroCnt) {
    int gtid = blockIdx.x * 256 + threadIdx.x;
    if (gtid < zeroCnt) zeroBuf[gtid] = 0.f;
    constexpr int C8 = O / 8;      // uint4 chunks per feature row: 4 / 8 / 16
    constexpr int EPP = 16 / C8;   // edges gathered per pass: 4 / 2 / 1
    int tid = threadIdx.x;
    int v = blockIdx.x * 16 + (tid >> 4);
    int l = tid & 15;              // lane within node group
    int gbase = tid & 48;          // group base lane within the 64-lane wave
    if (v >= n) return;
    int beg = rowptr[v], end = rowptr[v + 1];
    int deg = end - beg;
    float adv = ad_[v];
    int sub = l / C8;              // edge slot within pass (0..EPP-1)
    int c = l % C8;                // uint4 chunk within row
    float acc[8] = {0.f, 0.f, 0.f, 0.f, 0.f, 0.f, 0.f, 0.f};
    if (deg <= 16) {
        int sreg = v;
        float e = -1e30f;
        if (l < deg) {
            sreg = esrc[beg + l];
            float t = as_[sreg] + adv;
            e = (t > 0.f) ? t : 0.2f * t;
        }
        float m = e;
#pragma unroll
        for (int o = 8; o > 0; o >>= 1) m = fmaxf(m, __shfl_xor(m, o));
        float ex = (l < deg) ? __expf(e - m) : 0.f;
        float sum = ex;
#pragma unroll
        for (int o = 8; o > 0; o >>= 1) sum += __shfl_xor(sum, o);
        float alpha_r = ex / sum;
        for (int j0 = 0; j0 < deg; j0 += EPP) {
            int idx = j0 + sub;
            int cidx = (idx < deg) ? idx : 0;
            float alpha = __shfl(alpha_r, gbase + cidx);
            int s2 = __shfl(sreg, gbase + cidx);
            if (idx >= deg) alpha = 0.f;
            uint4 raw = ((const uint4*)(hl + (size_t)s2 * O))[c];
            acc[0] += alpha * __uint_as_float(raw.x << 16);
            acc[1] += alpha * __uint_as_float(raw.x & 0xffff0000u);
            acc[2] += alpha * __uint_as_float(raw.y << 16);
            acc[3] += alpha * __uint_as_float(raw.y & 0xffff0000u);
            acc[4] += alpha * __uint_as_float(raw.z << 16);
            acc[5] += alpha * __uint_as_float(raw.z & 0xffff0000u);
            acc[6] += alpha * __uint_as_float(raw.w << 16);
            acc[7] += alpha * __uint_as_float(raw.w & 0xffff0000u);
        }
    } else {
        // generic 16-lane path (deg > 16; ~1e-5 of nodes for this graph)
        float mymax = -1e30f;
        for (int j = beg + l; j < end; j += 16) {
            float e = as_[esrc[j]] + adv;
            e = (e > 0.f) ? e : 0.2f * e;
            mymax = fmaxf(mymax, e);
        }
#pragma unroll
        for (int o = 8; o > 0; o >>= 1) mymax = fmaxf(mymax, __shfl_xor(mymax, o));
        float mysum = 0.f;
        for (int j = beg + l; j < end; j += 16) {
            float e = as_[esrc[j]] + adv;
            e = (e > 0.f) ? e : 0.2f * e;
            mysum += __expf(e - mymax);
        }
#pragma unroll
        for (int o = 8; o > 0; o >>= 1) mysum += __shfl_xor(mysum, o);
        float invden = 1.f / mysum;
        for (int j0 = beg; j0 < end; j0 += EPP) {
            int j = j0 + sub;
            bool valid = j < end;
            int s = valid ? esrc[j] : v;
            float e = as_[s] + adv;
            e = (e > 0.f) ? e : 0.2f * e;
            float alpha = valid ? __expf(e - mymax) * invden : 0.f;
            uint4 raw = ((const uint4*)(hl + (size_t)s * O))[c];
            acc[0] += alpha * __uint_as_float(raw.x << 16);
            acc[1] += alpha * __uint_as_float(raw.x & 0xffff0000u);
            acc[2] += alpha * __uint_as_float(raw.y << 16);
            acc[3] += alpha * __uint_as_float(raw.y & 0xffff0000u);
            acc[4] += alpha * __uint_as_float(raw.z << 16);
            acc[5] += alpha * __uint_as_float(raw.z & 0xffff0000u);
            acc[6] += alpha * __uint_as_float(raw.w << 16);
            acc[7] += alpha * __uint_as_float(raw.w & 0xffff0000u);
        }
    }
#pragma unroll
    for (int o = C8; o < 16; o <<= 1)
#pragma unroll
        for (int k = 0; k < 8; k++) acc[k] += __shfl_xor(acc[k], o);
    if (l < C8) {
        unsigned short ov[8];
#pragma unroll
        for (int k = 0; k < 8; k++) {
            float val = acc[k];
            if constexpr (BIASRELU) val = fmaxf(val + bias[c * 8 + k], 0.f);
            ov[k] = f2bf(val);
        }
        uint4 packed;
        packed.x = (unsigned)ov[0] | ((unsigned)ov[1] << 16);
        packed.y = (unsigned)ov[2] | ((unsigned)ov[3] << 16);
        packed.z = (unsigned)ov[4] | ((unsigned)ov[5] << 16);
        packed.w = (unsigned)ov[6] | ((unsigned)ov[7] << 16);
        ((uint4*)(hout + (size_t)v * O))[c] = packed;
    }
}

// ---------------- fused mean-pool + linear + sigmoid: one block per graph ----------------
__global__ __launch_bounds__(256) void pool_final_kernel(
    const unsigned short* __restrict__ h, const int* __restrict__ start,
    const float* __restrict__ lw, const float* __restrict__ lb,
    float* __restrict__ out, int G) {
    __shared__ float red[8][33];
    int g = blockIdx.x;
    if (g >= G) return;
    int beg = start[g], end = start[g + 1];
    int tid = threadIdx.x;
    int nodeLane = tid >> 5, f = tid & 31;
    float acc = 0.f;
    for (int v = beg + nodeLane; v < end; v += 8)
        acc += bf2f(h[(size_t)v * 32 + f]);
    red[nodeLane][f] = acc;
    __syncthreads();
    if (tid < 32) {
        float s = 0.f;
#pragma unroll
        for (int i = 0; i < 8; i++) s += red[i][f];
        float inv = 1.f / fmaxf((float)(end - beg), 1.f);
        float val = s * inv * lw[f];
#pragma unroll
        for (int o = 16; o > 0; o >>= 1) val += __shfl_xor(val, o);
        if (f == 0) out[g] = 1.f / (1.f + __expf(-(val + lb[0])));
    }
}

extern "C" void kernel_launch(void* const* d_in, const int* in_sizes, int n_in,
                              void* d_out, int out_size, void* d_ws, size_t ws_size,
                              hipStream_t stream) {
    const float* x = (const float*)d_in[0];
    const int* ei = (const int*)d_in[1];
    const int* batch = (const int*)d_in[2];
    const float* w1 = (const float*)d_in[3];
    const float* b1 = (const float*)d_in[4];
    const float* w2 = (const float*)d_in[5];
    const float* b2 = (const float*)d_in[6];
    const float* w3 = (const float*)d_in[7];
    const float* b3 = (const float*)d_in[8];
    const float* gw[5];
    const float* gas[5];
    const float* gad[5];
    const float* gb[5];
    for (int l = 0; l < 5; l++) {
        gw[l] = (const float*)d_in[9 + l * 4 + 0];
        gas[l] = (const float*)d_in[9 + l * 4 + 1];
        gad[l] = (const float*)d_in[9 + l * 4 + 2];
        gb[l] = (const float*)d_in[9 + l * 4 + 3];
    }
    const float* lw = (const float*)d_in[29];
    const float* lb = (const float*)d_in[30];
    float* out = (float*)d_out;

    int N = in_sizes[0];
    int E = in_sizes[1] / 2;
    int G = out_size;
    int Etot = E + N;

    char* ws = (char*)d_ws;
    size_t off = 0;
    auto alloc = [&](size_t bytes) -> void* {
        void* p = ws + off;
        off = (off + bytes + 255) & ~(size_t)255;
        return p;
    };
    unsigned short* actA = (unsigned short*)alloc((size_t)N * 256 * 2);
    unsigned short* actB = (unsigned short*)alloc((size_t)N * 256 * 2);
    // zero-block: sd2 (2N f32) | sd3 (2N f32) | deg (N i32) — one memset
    char* zblock = (char*)alloc((size_t)N * 20);
    float* sd2 = (float*)zblock;
    float* sd3 = sd2 + (size_t)N * 2;
    int* deg = (int*)(zblock + (size_t)N * 16);
    float* sd1 = (float*)alloc((size_t)N * 2 * 4);  // direct-write, no zeroing needed
    float* pv2 = (float*)alloc(256 * 4);
    int* rowptr = (int*)alloc((size_t)(N + 1) * 4);
    int* cursor = (int*)alloc((size_t)(N + 1) * 4);
    int* esrc = (int*)alloc((size_t)Etot * 4);
    int* bsums = (int*)alloc(4096);
    int* gstart = (int*)alloc((size_t)(G + 1) * 4);
    unsigned short* wbAll = (unsigned short*)alloc((size_t)83968 * 2);
    const int woff[5] = {0, 8192, 40960, 73728, 81920};
    unsigned short* wb[5];
    for (int l = 0; l < 5; l++) wb[l] = wbAll + woff[l];
    (void)ws_size;
    (void)n_in;

    // 0. zero sd2|sd3|deg in one memset
    hipMemsetAsync(zblock, 0, (size_t)N * 20, stream);

    // 1. prelude: mlp (+s1/d1) + weight cast + graph starts + degree hist + pv2
    int mlpB = (N + 255) / 256;
    int f2bfB = (83968 + 255) / 256;
    int gsB = (G + 1 + 255) / 256;
    int histB = (Etot + 255) / 256;
    prelude_kernel<<<mlpB + f2bfB + gsB + histB + 1, 256, 0, stream>>>(
        x, w1, b1, w2, b2, w3, b3, actA, N, gw[0], gw[1], gw[2], gw[3], gw[4], wbAll, batch,
        gstart, G, ei + E, deg, E, mlpB, f2bfB, gsB, histB,
        gas[0], gad[0], sd1, sd1 + N, gas[1], gad[1], pv2);

    // 2. CSR scan + scatter
    int nb = (N + 1023) / 1024;
    scan_block_sums<<<nb, 256, 0, stream>>>(deg, bsums, N);
    scan_write<<<nb, 256, 0, stream>>>(deg, bsums, rowptr, cursor, N, nb);
    scatter_kernel<<<(Etot + 255) / 256, 256, 0, stream>>>(ei, ei + E, cursor, esrc, E, N);

    int aggBlocks = (N + 15) / 16;  // 16 nodes per block (16-lane groups)
    int gx = (N + 127) / 128;

    // 3. Layer 1 (64->128), scheme A: aggregate X1 (64-dim), then GEMM with bias+relu
    //    GEMM1 epilogue also computes s2/d2 = relu(X2)·pv2 into sd2 (pre-zeroed).
    //    BN=128: one A-pass (grid y = 1).
    gat_aggregate<64, false><<<aggBlocks, 256, 0, stream>>>(
        actA, sd1, sd1 + N, rowptr, esrc, nullptr, actB, N, nullptr, 0);
    {
        dim3 grid(gx, 1);
        gemm_mfma<128, 1><<<grid, 256, 0, stream>>>(actB, wb[0], actA, pv2, pv2 + 128, sd2,
                                                    sd2 + N, gb[0], N, 64, 128);
    }

    // 4. Layer 2 (128->256), scheme A: aggregate X2 (128-dim), then GEMM with bias+relu.
    //    agg2 chore: zero sd1 (reused as layer-4 accumulator). BN=128: 2 A-passes (was 4).
    gat_aggregate<128, false><<<aggBlocks, 256, 0, stream>>>(
        actA, sd2, sd2 + N, rowptr, esrc, nullptr, actB, N, sd1, 2 * N);
    {
        dim3 grid(gx, 2);
        gemm_mfma<128, 2><<<grid, 256, 0, stream>>>(actB, wb[1], actA, nullptr, nullptr,
                                                    nullptr, nullptr, gb[1], N, 128, 256);
    }

    // 5. Layer 3 (256->128), scheme T: GEMM raw (dot a_s3/a_d3 -> sd3), then aggregate
    //    with bias+relu. agg3 chore: zero sd2 (reused as layer-5 accumulator).
    //    BN=128: one A-pass (was 2).
    {
        dim3 grid(gx, 1);
        gemm_mfma<128, 0><<<grid, 256, 0, stream>>>(actA, wb[2], actB, gas[2], gad[2], sd3,
                                                    sd3 + N, nullptr, N, 256, 128);
    }
    gat_aggregate<128, true><<<aggBlocks, 256, 0, stream>>>(
        actB, sd3, sd3 + N, rowptr, esrc, gb[2], actA, N, sd2, 2 * N);

    // 6. Layer 4 (128->64), scheme T: dot -> sd1 (zeroed by agg2 chore)
    {
        dim3 grid(gx, 1);
        gemm_mfma<64, 0><<<grid, 256, 0, stream>>>(actA, wb[3], actB, gas[3], gad[3], sd1,
                                                   sd1 + N, nullptr, N, 128, 64);
    }
    gat_aggregate<64, true><<<aggBlocks, 256, 0, stream>>>(
        actB, sd1, sd1 + N, rowptr, esrc, gb[3], actA, N, nullptr, 0);

    // 7. Layer 5 (64->32), scheme T: dot -> sd2 (zeroed by agg3 chore)
    {
        dim3 grid(gx, 1);
        gemm_mfma<32, 0><<<grid, 256, 0, stream>>>(actA, wb[4], actB, gas[4], gad[4], sd2,
                                                   sd2 + N, nullptr, N, 64, 32);
    }
    gat_aggregate<32, true><<<aggBlocks, 256, 0, stream>>>(
        actB, sd2, sd2 + N, rowptr, esrc, gb[4], actA, N, nullptr, 0);

    // 8. fused mean pool + linear + sigmoid
    pool_final_kernel<<<G, 256, 0, stream>>>(actA, gstart, lw, lb, out, G);
}

// Round 4
// 459.170 us; speedup vs baseline: 1.0514x; 1.0514x over previous
//
#include <hip/hip_runtime.h>
#include <math.h>

typedef __attribute__((ext_vector_type(8))) __bf16 bf16x8;
typedef __attribute__((ext_vector_type(4))) float f32x4;

__device__ inline unsigned short f2bf(float f) {  // RNE
    unsigned int i = __float_as_uint(f);
    unsigned int r = i + 0x7fffu + ((i >> 16) & 1u);
    return (unsigned short)(r >> 16);
}
__device__ inline float bf2f(unsigned short u) {
    return __uint_as_float(((unsigned int)u) << 16);
}

// ---------------- prelude: MLP(+s1/d1) + weight-cast + graph starts + degree hist + pv2 ----
// Block ranges: [0,mlpB) mlp | [+f2bfB) weight cast | [+gsB) graph starts | [+histB) hist |
// last block: pv2 = W2^T {a_s2, a_d2}.
// MLP: 4 threads/node, 64 nodes/block (mlpB = ceil(N/64) -> ~6 blocks/CU: latency hidden
// by TLP; 1 node/thread at 391 blocks was 1.5 waves/SIMD and latency-bound). Weights in
// LDS read as float4 (ds_read_b128). w3 rows padded to 9 float4; thread sub owns output
// pairs o = 8p+2*sub so concurrent row reads are 8 banks apart (conflict-free).
__global__ __launch_bounds__(256) void prelude_kernel(
    const float* __restrict__ x,
    const float* __restrict__ w1, const float* __restrict__ b1,
    const float* __restrict__ w2, const float* __restrict__ b2,
    const float* __restrict__ w3, const float* __restrict__ b3,
    unsigned short* __restrict__ h0, int n,
    const float* __restrict__ g0, const float* __restrict__ g1, const float* __restrict__ g2,
    const float* __restrict__ g3, const float* __restrict__ g4,
    unsigned short* __restrict__ wbAll,
    const int* __restrict__ batch, int* __restrict__ gstart, int G,
    const int* __restrict__ dst, int* __restrict__ deg, int E,
    int mlpB, int f2bfB, int gsB, int histB,
    const float* __restrict__ as1, const float* __restrict__ ad1,
    float* __restrict__ s1out, float* __restrict__ d1out,
    const float* __restrict__ as2, const float* __restrict__ ad2,
    float* __restrict__ pv2) {
    int b = blockIdx.x;
    int tid = threadIdx.x;
    if (b < mlpB) {
        __shared__ float sw1[16], sb1[16], sb2[32], sb3[64];
        __shared__ float4 sw2q[128];      // w2 [32][16] as 4 float4/row
        __shared__ float4 sw3q[576];      // w3 [64][32] as 8 float4/row, row stride 9
        __shared__ float4 psd1q[32];      // interleaved {s,d}: ((float2*)psd1q)[o]
        if (tid < 16) { sw1[tid] = w1[tid]; sb1[tid] = b1[tid]; }
        if (tid < 32) sb2[tid] = b2[tid];
        if (tid < 64) sb3[tid] = b3[tid];
        for (int i = tid; i < 128; i += 256) sw2q[i] = ((const float4*)w2)[i];
        for (int i = tid; i < 512; i += 256)
            sw3q[(i >> 3) * 9 + (i & 7)] = ((const float4*)w3)[i];
        if (tid >= 192) {  // p-vec for layer 1: p = W1^T a  (g0 is g1w, [128][64])
            int i = tid - 192;
            float s = 0.f, d = 0.f;
            for (int o = 0; o < 128; o++) {
                float w = g0[o * 64 + i];
                s += as1[o] * w;
                d += ad1[o] * w;
            }
            ((float2*)psd1q)[i] = make_float2(s, d);
        }
        __syncthreads();
        int node = b * 64 + (tid >> 2);
        int sub = tid & 3;
        if (node >= n) return;
        float xv = x[node];
        float t1[16], t2[32];
#pragma unroll
        for (int i = 0; i < 16; i++) t1[i] = fmaxf(sw1[i] * xv + sb1[i], 0.f);
#pragma unroll
        for (int o = 0; o < 32; o++) {
            float a = sb2[o];
#pragma unroll
            for (int q = 0; q < 4; q++) {
                float4 wv = sw2q[o * 4 + q];
                a += wv.x * t1[q * 4] + wv.y * t1[q * 4 + 1] + wv.z * t1[q * 4 + 2] +
                     wv.w * t1[q * 4 + 3];
            }
            t2[o] = fmaxf(a, 0.f);
        }
        float sdot = 0.f, ddot = 0.f;
        unsigned int* gpw = (unsigned int*)(h0 + (size_t)node * 64);
#pragma unroll
        for (int p = 0; p < 8; p++) {
            int o = p * 8 + sub * 2;
            float a0 = sb3[o], a1 = sb3[o + 1];
#pragma unroll
            for (int q = 0; q < 8; q++) {
                float4 wa = sw3q[o * 9 + q];
                float4 wb = sw3q[(o + 1) * 9 + q];
                a0 += wa.x * t2[q * 4] + wa.y * t2[q * 4 + 1] + wa.z * t2[q * 4 + 2] +
                      wa.w * t2[q * 4 + 3];
                a1 += wb.x * t2[q * 4] + wb.y * t2[q * 4 + 1] + wb.z * t2[q * 4 + 2] +
                      wb.w * t2[q * 4 + 3];
            }
            float r0 = fmaxf(a0, 0.f), r1 = fmaxf(a1, 0.f);
            float4 qsd = psd1q[o >> 1];  // {s_o, d_o, s_{o+1}, d_{o+1}}
            sdot += r0 * qsd.x + r1 * qsd.z;
            ddot += r0 * qsd.y + r1 * qsd.w;
            gpw[p * 4 + sub] = (unsigned)f2bf(r0) | ((unsigned)f2bf(r1) << 16);
        }
        sdot += __shfl_xor(sdot, 1);
        sdot += __shfl_xor(sdot, 2);
        ddot += __shfl_xor(ddot, 1);
        ddot += __shfl_xor(ddot, 2);
        if (sub == 0) {
            s1out[node] = sdot;
            d1out[node] = ddot;
        }
    } else if (b < mlpB + f2bfB) {
        int i = (b - mlpB) * 256 + tid;
        // segment offsets: 0, 8192, 40960, 73728, 81920, end 83968
        float v;
        if (i < 8192) v = g0[i];
        else if (i < 40960) v = g1[i - 8192];
        else if (i < 73728) v = g2[i - 40960];
        else if (i < 81920) v = g3[i - 73728];
        else if (i < 83968) v = g4[i - 81920];
        else return;
        wbAll[i] = f2bf(v);
    } else if (b < mlpB + f2bfB + gsB) {
        int g = (b - mlpB - f2bfB) * 256 + tid;
        if (g > G) return;
        if (g == G) { gstart[G] = n; return; }
        int lo = 0, hi = n;
        while (lo < hi) {
            int mid = (lo + hi) >> 1;
            if (batch[mid] < g) lo = mid + 1;
            else hi = mid;
        }
        gstart[g] = lo;
    } else if (b < mlpB + f2bfB + gsB + histB) {
        int e = (b - mlpB - f2bfB - gsB) * 256 + tid;
        if (e >= E + n) return;
        int d = (e < E) ? dst[e] : (e - E);
        atomicAdd(&deg[d], 1);
    } else {
        // pv2 = W2^T {a_s2 | a_d2}; g1 is g2w [256][128]
        if (tid < 128) {
            float s = 0.f;
            for (int o = 0; o < 256; o++) s += as2[o] * g1[o * 128 + tid];
            pv2[tid] = s;
        } else {
            int c = tid - 128;
            float s = 0.f;
            for (int o = 0; o < 256; o++) s += ad2[o] * g1[o * 128 + c];
            pv2[128 + c] = s;
        }
    }
}

// ---------------- bf16 MFMA GEMM, 128xBN tile, BK=64 ----------------
// EPI: 0 = raw store + raw-acc dot with avs/avd (scheme-T layers)
//      1 = bias+relu store + post-relu dot with avs/avd (feeds a scheme-A layer)
//      2 = bias+relu store only
template <int BN, int EPI>
__global__ __launch_bounds__(256) void gemm_mfma(
    const unsigned short* __restrict__ A, const unsigned short* __restrict__ Wb,
    unsigned short* __restrict__ Cb,
    const float* __restrict__ avs, const float* __restrict__ avd,
    float* __restrict__ as_, float* __restrict__ ad_,
    const float* __restrict__ bias, int n, int K, int O) {
    constexpr int SN = BN / 32;
    __shared__ unsigned short As[128][72];  // +8 pad: frag reads <=2-way banks (free)
    __shared__ unsigned short Ws[BN][72];
    int tid = threadIdx.x;
    int row0 = blockIdx.x * 128, col0 = blockIdx.y * BN;
    int w = tid >> 6, lane = tid & 63;
    int wr = w >> 1, wc = w & 1;
    int quad = lane >> 4, l15 = lane & 15;
    f32x4 acc[4][SN];
#pragma unroll
    for (int mi = 0; mi < 4; mi++)
#pragma unroll
        for (int ni = 0; ni < SN; ni++) acc[mi][ni] = (f32x4){0.f, 0.f, 0.f, 0.f};

    for (int k0 = 0; k0 < K; k0 += 64) {
#pragma unroll
        for (int i = tid; i < 1024; i += 256) {
            int r = i >> 3, c8 = i & 7;
            int gr = row0 + r;
            uint4 v = make_uint4(0u, 0u, 0u, 0u);
            if (gr < n) v = *(const uint4*)(A + (size_t)gr * K + k0 + c8 * 8);
            *(uint4*)&As[r][c8 * 8] = v;
        }
#pragma unroll
        for (int i = tid; i < BN * 8; i += 256) {
            int r = i >> 3, c8 = i & 7;
            uint4 v = *(const uint4*)(Wb + (size_t)(col0 + r) * K + k0 + c8 * 8);
            *(uint4*)&Ws[r][c8 * 8] = v;
        }
        __syncthreads();
#pragma unroll
        for (int kk = 0; kk < 64; kk += 32) {
            bf16x8 bfr[SN];
#pragma unroll
            for (int ni = 0; ni < SN; ni++)
                bfr[ni] = *(const bf16x8*)&Ws[wc * (BN / 2) + ni * 16 + l15][kk + quad * 8];
#pragma unroll
            for (int mi = 0; mi < 4; mi++) {
                bf16x8 afr = *(const bf16x8*)&As[wr * 64 + mi * 16 + l15][kk + quad * 8];
#pragma unroll
                for (int ni = 0; ni < SN; ni++)
                    acc[mi][ni] = __builtin_amdgcn_mfma_f32_16x16x32_bf16(afr, bfr[ni],
                                                                          acc[mi][ni], 0, 0, 0);
            }
        }
        __syncthreads();
    }
    float avsv[SN], avdv[SN], bv[SN];
    int gc[SN];
#pragma unroll
    for (int ni = 0; ni < SN; ni++) {
        gc[ni] = col0 + wc * (BN / 2) + ni * 16 + l15;
        if constexpr (EPI != 2) {
            avsv[ni] = avs[gc[ni]];
            avdv[ni] = avd[gc[ni]];
        }
        if constexpr (EPI >= 1) bv[ni] = bias[gc[ni]];
    }
#pragma unroll
    for (int mi = 0; mi < 4; mi++) {
        int gm0 = row0 + wr * 64 + mi * 16 + quad * 4;
        float ps[4] = {0.f, 0.f, 0.f, 0.f}, pd[4] = {0.f, 0.f, 0.f, 0.f};
#pragma unroll
        for (int ni = 0; ni < SN; ni++) {
#pragma unroll
            for (int r = 0; r < 4; r++) {
                float d = acc[mi][ni][r];
                if constexpr (EPI >= 1) d = fmaxf(d + bv[ni], 0.f);
                int gm = gm0 + r;
                if (gm < n) Cb[(size_t)gm * O + gc[ni]] = f2bf(d);
                if constexpr (EPI != 2) {
                    ps[r] += d * avsv[ni];
                    pd[r] += d * avdv[ni];
                }
            }
        }
        if constexpr (EPI != 2) {
#pragma unroll
            for (int r = 0; r < 4; r++) {
#pragma unroll
                for (int m = 1; m <= 8; m <<= 1) {
                    ps[r] += __shfl_xor(ps[r], m);
                    pd[r] += __shfl_xor(pd[r], m);
                }
            }
            if (l15 == 0) {
#pragma unroll
                for (int r = 0; r < 4; r++) {
                    int gm = gm0 + r;
                    if (gm < n) {
                        atomicAdd(&as_[gm], ps[r]);
                        atomicAdd(&ad_[gm], pd[r]);
                    }
                }
            }
        }
    }
}

// ---------------- scan: per-1024-chunk sums ----------------
__global__ void scan_block_sums(const int* __restrict__ deg, int* __restrict__ bsums, int n) {
    __shared__ int sdata[256];
    int tid = threadIdx.x;
    int base = blockIdx.x * 1024 + tid * 4;
    int s = 0;
    for (int i = 0; i < 4; i++) {
        int g = base + i;
        if (g < n) s += deg[g];
    }
    sdata[tid] = s;
    __syncthreads();
    for (int off = 128; off > 0; off >>= 1) {
        if (tid < off) sdata[tid] += sdata[tid + off];
        __syncthreads();
    }
    if (tid == 0) bsums[blockIdx.x] = sdata[0];
}

// ---------------- scan_write: inline bsums prefix (nb <= 256) + rowptr/cursor ----------------
__global__ void scan_write(const int* __restrict__ deg, const int* __restrict__ bsums,
                           int* __restrict__ rowptr, int* __restrict__ cursor, int n, int nb) {
    __shared__ int sdata[256];
    int tid = threadIdx.x;
    sdata[tid] = (tid < blockIdx.x && tid < nb) ? bsums[tid] : 0;
    __syncthreads();
    for (int off = 128; off > 0; off >>= 1) {
        if (tid < off) sdata[tid] += sdata[tid + off];
        __syncthreads();
    }
    int base = sdata[0];
    __syncthreads();
    int gbase = blockIdx.x * 1024 + tid * 4;
    int v[4];
    int s = 0;
    for (int i = 0; i < 4; i++) {
        int g = gbase + i;
        v[i] = (g < n) ? deg[g] : 0;
        s += v[i];
    }
    sdata[tid] = s;
    __syncthreads();
    for (int off = 1; off < 256; off <<= 1) {  // inclusive Hillis-Steele
        int t = (tid >= off) ? sdata[tid - off] : 0;
        __syncthreads();
        sdata[tid] += t;
        __syncthreads();
    }
    int excl = sdata[tid] - s + base;
    for (int i = 0; i < 4; i++) {
        int g = gbase + i;
        if (g < n) { rowptr[g] = excl; cursor[g] = excl; }
        excl += v[i];
    }
    if (blockIdx.x == gridDim.x - 1 && tid == 255) rowptr[n] = base + sdata[255];
}

__global__ void scatter_kernel(const int* __restrict__ esrc_in, const int* __restrict__ edst_in,
                               int* __restrict__ cursor, int* __restrict__ esrc, int E, int n) {
    int e = blockIdx.x * 256 + threadIdx.x;
    if (e >= E + n) return;
    int s, d;
    if (e < E) { s = esrc_in[e]; d = edst_in[e]; }
    else { s = e - E; d = e - E; }
    int pos = atomicAdd(&cursor[d], 1);
    esrc[pos] = s;
}

// ---------------- GAT aggregation: 16-lane group per dst node (4 nodes/wave) ----------------
// BIASRELU=false: scheme-A (aggregate-first) — raw weighted sum, bias/relu applied by the
// following GEMM. BIASRELU=true: scheme-T — add bias, relu.
// Fast path deg<=16: one edge per group lane; all shuffles (xor masks <16, computed src
// lanes (lane&48)|cidx) stay inside the 16-lane group.
// Also zeroes zeroBuf (a later layer's alpha accumulators) as a grid-stride chore.
template <int O, bool BIASRELU>
__global__ __launch_bounds__(256) void gat_aggregate(
    const unsigned short* __restrict__ hl, const float* __restrict__ as_,
    const float* __restrict__ ad_, const int* __restrict__ rowptr,
    const int* __restrict__ esrc, const float* __restrict__ bias,
    unsigned short* __restrict__ hout, int n, float* __restrict__ zeroBuf, int zeroCnt) {
    int gtid = blockIdx.x * 256 + threadIdx.x;
    if (gtid < zeroCnt) zeroBuf[gtid] = 0.f;
    constexpr int C8 = O / 8;      // uint4 chunks per feature row: 4 / 8 / 16
    constexpr int EPP = 16 / C8;   // edges gathered per pass: 4 / 2 / 1
    int tid = threadIdx.x;
    int v = blockIdx.x * 16 + (tid >> 4);
    int l = tid & 15;              // lane within node group
    int gbase = tid & 48;          // group base lane within the 64-lane wave
    if (v >= n) return;
    int beg = rowptr[v], end = rowptr[v + 1];
    int deg = end - beg;
    float adv = ad_[v];
    int sub = l / C8;              // edge slot within pass (0..EPP-1)
    int c = l % C8;                // uint4 chunk within row
    float acc[8] = {0.f, 0.f, 0.f, 0.f, 0.f, 0.f, 0.f, 0.f};
    if (deg <= 16) {
        int sreg = v;
        float e = -1e30f;
        if (l < deg) {
            sreg = esrc[beg + l];
            float t = as_[sreg] + adv;
            e = (t > 0.f) ? t : 0.2f * t;
        }
        float m = e;
#pragma unroll
        for (int o = 8; o > 0; o >>= 1) m = fmaxf(m, __shfl_xor(m, o));
        float ex = (l < deg) ? __expf(e - m) : 0.f;
        float sum = ex;
#pragma unroll
        for (int o = 8; o > 0; o >>= 1) sum += __shfl_xor(sum, o);
        float alpha_r = ex / sum;
        for (int j0 = 0; j0 < deg; j0 += EPP) {
            int idx = j0 + sub;
            int cidx = (idx < deg) ? idx : 0;
            float alpha = __shfl(alpha_r, gbase + cidx);
            int s2 = __shfl(sreg, gbase + cidx);
            if (idx >= deg) alpha = 0.f;
            uint4 raw = ((const uint4*)(hl + (size_t)s2 * O))[c];
            acc[0] += alpha * __uint_as_float(raw.x << 16);
            acc[1] += alpha * __uint_as_float(raw.x & 0xffff0000u);
            acc[2] += alpha * __uint_as_float(raw.y << 16);
            acc[3] += alpha * __uint_as_float(raw.y & 0xffff0000u);
            acc[4] += alpha * __uint_as_float(raw.z << 16);
            acc[5] += alpha * __uint_as_float(raw.z & 0xffff0000u);
            acc[6] += alpha * __uint_as_float(raw.w << 16);
            acc[7] += alpha * __uint_as_float(raw.w & 0xffff0000u);
        }
    } else {
        // generic 16-lane path (deg > 16; ~1e-5 of nodes for this graph)
        float mymax = -1e30f;
        for (int j = beg + l; j < end; j += 16) {
            float e = as_[esrc[j]] + adv;
            e = (e > 0.f) ? e : 0.2f * e;
            mymax = fmaxf(mymax, e);
        }
#pragma unroll
        for (int o = 8; o > 0; o >>= 1) mymax = fmaxf(mymax, __shfl_xor(mymax, o));
        float mysum = 0.f;
        for (int j = beg + l; j < end; j += 16) {
            float e = as_[esrc[j]] + adv;
            e = (e > 0.f) ? e : 0.2f * e;
            mysum += __expf(e - mymax);
        }
#pragma unroll
        for (int o = 8; o > 0; o >>= 1) mysum += __shfl_xor(mysum, o);
        float invden = 1.f / mysum;
        for (int j0 = beg; j0 < end; j0 += EPP) {
            int j = j0 + sub;
            bool valid = j < end;
            int s = valid ? esrc[j] : v;
            float e = as_[s] + adv;
            e = (e > 0.f) ? e : 0.2f * e;
            float alpha = valid ? __expf(e - mymax) * invden : 0.f;
            uint4 raw = ((const uint4*)(hl + (size_t)s * O))[c];
            acc[0] += alpha * __uint_as_float(raw.x << 16);
            acc[1] += alpha * __uint_as_float(raw.x & 0xffff0000u);
            acc[2] += alpha * __uint_as_float(raw.y << 16);
            acc[3] += alpha * __uint_as_float(raw.y & 0xffff0000u);
            acc[4] += alpha * __uint_as_float(raw.z << 16);
            acc[5] += alpha * __uint_as_float(raw.z & 0xffff0000u);
            acc[6] += alpha * __uint_as_float(raw.w << 16);
            acc[7] += alpha * __uint_as_float(raw.w & 0xffff0000u);
        }
    }
#pragma unroll
    for (int o = C8; o < 16; o <<= 1)
#pragma unroll
        for (int k = 0; k < 8; k++) acc[k] += __shfl_xor(acc[k], o);
    if (l < C8) {
        unsigned short ov[8];
#pragma unroll
        for (int k = 0; k < 8; k++) {
            float val = acc[k];
            if constexpr (BIASRELU) val = fmaxf(val + bias[c * 8 + k], 0.f);
            ov[k] = f2bf(val);
        }
        uint4 packed;
        packed.x = (unsigned)ov[0] | ((unsigned)ov[1] << 16);
        packed.y = (unsigned)ov[2] | ((unsigned)ov[3] << 16);
        packed.z = (unsigned)ov[4] | ((unsigned)ov[5] << 16);
        packed.w = (unsigned)ov[6] | ((unsigned)ov[7] << 16);
        ((uint4*)(hout + (size_t)v * O))[c] = packed;
    }
}

// ---------------- fused mean-pool + linear + sigmoid: one block per graph ----------------
__global__ __launch_bounds__(256) void pool_final_kernel(
    const unsigned short* __restrict__ h, const int* __restrict__ start,
    const float* __restrict__ lw, const float* __restrict__ lb,
    float* __restrict__ out, int G) {
    __shared__ float red[8][33];
    int g = blockIdx.x;
    if (g >= G) return;
    int beg = start[g], end = start[g + 1];
    int tid = threadIdx.x;
    int nodeLane = tid >> 5, f = tid & 31;
    float acc = 0.f;
    for (int v = beg + nodeLane; v < end; v += 8)
        acc += bf2f(h[(size_t)v * 32 + f]);
    red[nodeLane][f] = acc;
    __syncthreads();
    if (tid < 32) {
        float s = 0.f;
#pragma unroll
        for (int i = 0; i < 8; i++) s += red[i][f];
        float inv = 1.f / fmaxf((float)(end - beg), 1.f);
        float val = s * inv * lw[f];
#pragma unroll
        for (int o = 16; o > 0; o >>= 1) val += __shfl_xor(val, o);
        if (f == 0) out[g] = 1.f / (1.f + __expf(-(val + lb[0])));
    }
}

extern "C" void kernel_launch(void* const* d_in, const int* in_sizes, int n_in,
                              void* d_out, int out_size, void* d_ws, size_t ws_size,
                              hipStream_t stream) {
    const float* x = (const float*)d_in[0];
    const int* ei = (const int*)d_in[1];
    const int* batch = (const int*)d_in[2];
    const float* w1 = (const float*)d_in[3];
    const float* b1 = (const float*)d_in[4];
    const float* w2 = (const float*)d_in[5];
    const float* b2 = (const float*)d_in[6];
    const float* w3 = (const float*)d_in[7];
    const float* b3 = (const float*)d_in[8];
    const float* gw[5];
    const float* gas[5];
    const float* gad[5];
    const float* gb[5];
    for (int l = 0; l < 5; l++) {
        gw[l] = (const float*)d_in[9 + l * 4 + 0];
        gas[l] = (const float*)d_in[9 + l * 4 + 1];
        gad[l] = (const float*)d_in[9 + l * 4 + 2];
        gb[l] = (const float*)d_in[9 + l * 4 + 3];
    }
    const float* lw = (const float*)d_in[29];
    const float* lb = (const float*)d_in[30];
    float* out = (float*)d_out;

    int N = in_sizes[0];
    int E = in_sizes[1] / 2;
    int G = out_size;
    int Etot = E + N;

    char* ws = (char*)d_ws;
    size_t off = 0;
    auto alloc = [&](size_t bytes) -> void* {
        void* p = ws + off;
        off = (off + bytes + 255) & ~(size_t)255;
        return p;
    };
    unsigned short* actA = (unsigned short*)alloc((size_t)N * 256 * 2);
    unsigned short* actB = (unsigned short*)alloc((size_t)N * 256 * 2);
    // zero-block: sd2 (2N f32) | sd3 (2N f32) | deg (N i32) — one memset
    char* zblock = (char*)alloc((size_t)N * 20);
    float* sd2 = (float*)zblock;
    float* sd3 = sd2 + (size_t)N * 2;
    int* deg = (int*)(zblock + (size_t)N * 16);
    float* sd1 = (float*)alloc((size_t)N * 2 * 4);  // direct-write, no zeroing needed
    float* pv2 = (float*)alloc(256 * 4);
    int* rowptr = (int*)alloc((size_t)(N + 1) * 4);
    int* cursor = (int*)alloc((size_t)(N + 1) * 4);
    int* esrc = (int*)alloc((size_t)Etot * 4);
    int* bsums = (int*)alloc(4096);
    int* gstart = (int*)alloc((size_t)(G + 1) * 4);
    unsigned short* wbAll = (unsigned short*)alloc((size_t)83968 * 2);
    const int woff[5] = {0, 8192, 40960, 73728, 81920};
    unsigned short* wb[5];
    for (int l = 0; l < 5; l++) wb[l] = wbAll + woff[l];
    (void)ws_size;
    (void)n_in;

    // 0. zero sd2|sd3|deg in one memset
    hipMemsetAsync(zblock, 0, (size_t)N * 20, stream);

    // 1. prelude: mlp (+s1/d1) + weight cast + graph starts + degree hist + pv2
    int mlpB = (N + 63) / 64;  // 4 threads/node, 64 nodes/block
    int f2bfB = (83968 + 255) / 256;
    int gsB = (G + 1 + 255) / 256;
    int histB = (Etot + 255) / 256;
    prelude_kernel<<<mlpB + f2bfB + gsB + histB + 1, 256, 0, stream>>>(
        x, w1, b1, w2, b2, w3, b3, actA, N, gw[0], gw[1], gw[2], gw[3], gw[4], wbAll, batch,
        gstart, G, ei + E, deg, E, mlpB, f2bfB, gsB, histB,
        gas[0], gad[0], sd1, sd1 + N, gas[1], gad[1], pv2);

    // 2. CSR scan + scatter
    int nb = (N + 1023) / 1024;
    scan_block_sums<<<nb, 256, 0, stream>>>(deg, bsums, N);
    scan_write<<<nb, 256, 0, stream>>>(deg, bsums, rowptr, cursor, N, nb);
    scatter_kernel<<<(Etot + 255) / 256, 256, 0, stream>>>(ei, ei + E, cursor, esrc, E, N);

    int aggBlocks = (N + 15) / 16;  // 16 nodes per block (16-lane groups)
    int gx = (N + 127) / 128;

    // 3. Layer 1 (64->128), scheme A: aggregate X1 (64-dim), then GEMM with bias+relu
    //    GEMM1 epilogue also computes s2/d2 = relu(X2)·pv2 into sd2 (pre-zeroed).
    gat_aggregate<64, false><<<aggBlocks, 256, 0, stream>>>(
        actA, sd1, sd1 + N, rowptr, esrc, nullptr, actB, N, nullptr, 0);
    {
        dim3 grid(gx, 2);
        gemm_mfma<64, 1><<<grid, 256, 0, stream>>>(actB, wb[0], actA, pv2, pv2 + 128, sd2,
                                                   sd2 + N, gb[0], N, 64, 128);
    }

    // 4. Layer 2 (128->256), scheme A: aggregate X2 (128-dim), then GEMM with bias+relu.
    //    agg2 chore: zero sd1 (reused as layer-4 accumulator).
    gat_aggregate<128, false><<<aggBlocks, 256, 0, stream>>>(
        actA, sd2, sd2 + N, rowptr, esrc, nullptr, actB, N, sd1, 2 * N);
    {
        dim3 grid(gx, 4);
        gemm_mfma<64, 2><<<grid, 256, 0, stream>>>(actB, wb[1], actA, nullptr, nullptr,
                                                   nullptr, nullptr, gb[1], N, 128, 256);
    }

    // 5. Layer 3 (256->128), scheme T: GEMM raw (dot a_s3/a_d3 -> sd3), then aggregate
    //    with bias+relu. agg3 chore: zero sd2 (reused as layer-5 accumulator).
    {
        dim3 grid(gx, 2);
        gemm_mfma<64, 0><<<grid, 256, 0, stream>>>(actA, wb[2], actB, gas[2], gad[2], sd3,
                                                   sd3 + N, nullptr, N, 256, 128);
    }
    gat_aggregate<128, true><<<aggBlocks, 256, 0, stream>>>(
        actB, sd3, sd3 + N, rowptr, esrc, gb[2], actA, N, sd2, 2 * N);

    // 6. Layer 4 (128->64), scheme T: dot -> sd1 (zeroed by agg2 chore)
    {
        dim3 grid(gx, 1);
        gemm_mfma<64, 0><<<grid, 256, 0, stream>>>(actA, wb[3], actB, gas[3], gad[3], sd1,
                                                   sd1 + N, nullptr, N, 128, 64);
    }
    gat_aggregate<64, true><<<aggBlocks, 256, 0, stream>>>(
        actB, sd1, sd1 + N, rowptr, esrc, gb[3], actA, N, nullptr, 0);

    // 7. Layer 5 (64->32), scheme T: dot -> sd2 (zeroed by agg3 chore)
    {
        dim3 grid(gx, 1);
        gemm_mfma<32, 0><<<grid, 256, 0, stream>>>(actA, wb[4], actB, gas[4], gad[4], sd2,
                                                   sd2 + N, nullptr, N, 64, 32);
    }
    gat_aggregate<32, true><<<aggBlocks, 256, 0, stream>>>(
        actB, sd2, sd2 + N, rowptr, esrc, gb[4], actA, N, nullptr, 0);

    // 8. fused mean pool + linear + sigmoid
    pool_final_kernel<<<G, 256, 0, stream>>>(actA, gstart, lw, lb, out, G);
}